// Round 1
// 989.632 us; speedup vs baseline: 1.0712x; 1.0712x over previous
//
#include <hip/hip_runtime.h>
#include <hip/hip_bf16.h>

#define NN 100000
#define EE 1600000

typedef unsigned short u16;
typedef unsigned int   u32;
typedef short short8 __attribute__((ext_vector_type(8)));
typedef float v4f    __attribute__((ext_vector_type(4)));

__device__ __forceinline__ float b2f(u16 h){ u32 u = ((u32)h) << 16; return __builtin_bit_cast(float, u); }
__device__ __forceinline__ float lo2f(u32 u){ return __builtin_bit_cast(float, u << 16); }
__device__ __forceinline__ float hi2f(u32 u){ return __builtin_bit_cast(float, u & 0xffff0000u); }
__device__ __forceinline__ u16   f2b(float f){ __hip_bfloat16 h = __float2bfloat16(f); return __builtin_bit_cast(u16, h); }
__device__ __forceinline__ float ldx(const void* p, long i, int fm){
  return fm ? ((const float*)p)[i] : b2f(((const u16*)p)[i]);
}
__device__ __forceinline__ float i2f(int v){ return __builtin_bit_cast(float, v); }

// ---------------- dtype detection (parallel) ----------------
__global__ void k_detect(const void* __restrict__ x, const void* __restrict__ nonlab,
                         int* __restrict__ flags){
  __shared__ int s_bad, s_ni, s_nf, s_nb;
  int t = threadIdx.x;
  if (t == 0){ s_bad = 0; s_ni = 0; s_nf = 0; s_nb = 0; }
  __syncthreads();
  u32 w = ((const u32*)x)[t];
  u32 lo = w & 0xffffu, ex = (lo >> 7) & 0xffu;
  if (lo != 0u && (ex < 100u || ex > 140u)) atomicAdd(&s_bad, 1);
  if (t < 64){
    u32 v = ((const u32*)nonlab)[t];
    if (v > 1u) atomicAdd(&s_ni, 1);
    if (v != 0u && v != 0x3F800000u) atomicAdd(&s_nf, 1);
  }
  if (t < 128){
    u16 h = ((const u16*)nonlab)[t];
    if (h != 0 && h != 0x3F80) atomicAdd(&s_nb, 1);
  }
  __syncthreads();
  if (t == 0){
    flags[0] = (s_bad > 32) ? 1 : 0;
    flags[1] = (s_ni == 0) ? 1 : ((s_nf == 0) ? 3 : ((s_nb == 0) ? 2 : 0));
  }
}

// ---------------- CSR build ----------------
__global__ void k_count(const int* __restrict__ ei, int* __restrict__ cnt){
  int e = blockIdx.x * 256 + threadIdx.x;
  if (e < EE) atomicAdd(&cnt[ei[e]], 1);
}

#define SCAN_C 1024
__global__ void k_scan1(const int* __restrict__ cnt, int* __restrict__ part){
  __shared__ int red[256];
  int b = blockIdx.x, t = threadIdx.x;
  int base = b * SCAN_C + t * 4;
  int s = 0;
  #pragma unroll
  for (int j = 0; j < 4; ++j){ int i = base + j; if (i < NN) s += cnt[i]; }
  red[t] = s; __syncthreads();
  for (int o = 128; o; o >>= 1){ if (t < o) red[t] += red[t + o]; __syncthreads(); }
  if (t == 0) part[b] = red[0];
}
__global__ void k_scan2(int* __restrict__ part, int* __restrict__ rowptr, int nb){
  __shared__ int l[128];
  int t = threadIdx.x;
  int v = (t < nb) ? part[t] : 0;
  l[t] = v; __syncthreads();
  for (int o = 1; o < 128; o <<= 1){
    int x = (t >= o) ? l[t - o] : 0; __syncthreads();
    l[t] += x; __syncthreads();
  }
  if (t < nb) part[t] = l[t] - v;          // exclusive
  if (t == nb - 1) rowptr[NN] = l[t];      // total == EE
}
__global__ void k_scan3(const int* __restrict__ cnt, const int* __restrict__ part,
                        int* __restrict__ rowptr){
  __shared__ int lds[256];
  int b = blockIdx.x, t = threadIdx.x;
  int base = b * SCAN_C + t * 4;
  int v[4]; int s = 0;
  #pragma unroll
  for (int j = 0; j < 4; ++j){ int i = base + j; v[j] = (i < NN) ? cnt[i] : 0; s += v[j]; }
  lds[t] = s; __syncthreads();
  for (int o = 1; o < 256; o <<= 1){
    int x = (t >= o) ? lds[t - o] : 0; __syncthreads();
    lds[t] += x; __syncthreads();
  }
  int excl = lds[t] - s + part[b];
  #pragma unroll
  for (int j = 0; j < 4; ++j){
    int i = base + j;
    if (i < NN){ rowptr[i] = excl; excl += v[j]; }
  }
}

// ---------------- bucketed scatter (replaces k_scatter) ----------------
// Coarse buckets of 512 rows each; bucket regions in cpk are exactly
// [rowptr[b*512], rowptr[(b+1)*512)) so sizing is exact (no overflow possible).
#define BSH 9
#define NBK 196   // ceil(NN / 512)

__global__ void k_binit(const int* __restrict__ rowptr, int* __restrict__ bcur){
  int t = threadIdx.x;
  if (t < NBK) bcur[t] = rowptr[t << BSH];
}

// Pass A: block-local LDS multisplit into coarse buckets; each (block,bucket)
// reserves one contiguous run via a single global atomic -> dense writes.
__global__ __launch_bounds__(256) void k_binA(const int* __restrict__ ei, const void* __restrict__ ew,
                      int* __restrict__ bcur, int2* __restrict__ stage,
                      const int* __restrict__ flags){
  __shared__ int lcnt[NBK];
  __shared__ int lbase[NBK];
  int t = threadIdx.x;
  for (int i = t; i < NBK; i += 256) lcnt[i] = 0;
  __syncthreads();
  int fm = flags[0];
  long e0 = (long)blockIdx.x * 4096;
  int bb[16], ord[16], pk[16], wb[16];
  #pragma unroll
  for (int j = 0; j < 16; ++j){
    long e = e0 + j * 256 + t;
    bool v = e < EE;
    int r = v ? ei[e] : 0;
    int c = v ? ei[EE + e] : 0;
    float w = v ? ldx(ew, e, fm) : 0.f;
    int b = r >> BSH;
    bb[j] = v ? b : -1;
    pk[j] = ((r & 511) << 17) | c;   // rowInBucket (9b) | col (17b)
    wb[j] = __builtin_bit_cast(int, w);
    if (v) ord[j] = atomicAdd(&lcnt[b], 1);
  }
  __syncthreads();
  for (int i = t; i < NBK; i += 256){
    int c = lcnt[i];
    lbase[i] = c ? atomicAdd(&bcur[i], c) : 0;
  }
  __syncthreads();
  #pragma unroll
  for (int j = 0; j < 16; ++j){
    if (bb[j] >= 0){
      int pos = lbase[bb[j]] + ord[j];
      stage[pos] = make_int2(pk[j], wb[j]);
    }
  }
}

// Pass B: one block per bucket; sequential read of the staged segment,
// exact-position scatter confined to the bucket's ~64KB window (L2-local).
__global__ __launch_bounds__(512) void k_binB(const int* __restrict__ rowptr,
                      const int2* __restrict__ stage, int2* __restrict__ cpk){
  __shared__ int cur[512];
  int b = blockIdx.x, t = threadIdx.x;
  int r0 = b << BSH;
  int rows = min(512, NN - r0);
  for (int i = t; i < rows; i += 512) cur[i] = rowptr[r0 + i];
  __syncthreads();
  int s = rowptr[r0];
  int e = rowptr[min(r0 + 512, NN)];
  for (int j = s + t; j < e; j += 512){
    int2 v = stage[j];
    int rib = ((u32)v.x) >> 17;
    int col = v.x & 0x1FFFF;
    int pos = atomicAdd(&cur[rib], 1);
    cpk[pos] = make_int2(col, v.y);
  }
}

// ---------------- SpMM: one wave per row, 8 edges in flight ----------------
template<int D, bool EXT>
__global__ __launch_bounds__(256) void k_spmm(const void* __restrict__ in, u16* __restrict__ out,
                       const int* __restrict__ rowptr, const int2* __restrict__ cpk,
                       const int* __restrict__ flags){
  int wid  = blockIdx.x * 4 + (threadIdx.x >> 6);
  int lane = threadIdx.x & 63;
  if (wid >= NN) return;
  int fm = EXT ? flags[0] : 0;
  int s = rowptr[wid], e = rowptr[wid + 1];
  float a0 = 0.f, a1 = 0.f, a2 = 0.f;
  int j = s;
  if (EXT && fm){
    const float* fin = (const float*)in;
    for (; j + 8 <= e; j += 8){
      int2 p[8];
      #pragma unroll
      for (int q = 0; q < 8; ++q) p[q] = cpk[j + q];
      float2 v[8];
      #pragma unroll
      for (int q = 0; q < 8; ++q) v[q] = *(const float2*)(fin + (long)p[q].x * D + 2 * lane);
      #pragma unroll
      for (int q = 0; q < 8; ++q){
        float wt = i2f(p[q].y);
        a0 = fmaf(wt, v[q].x, a0);
        a1 = fmaf(wt, v[q].y, a1);
      }
    }
    for (; j < e; ++j){
      int2 p = cpk[j]; float wt = i2f(p.y);
      float2 v = *(const float2*)(fin + (long)p.x * D + 2 * lane);
      a0 = fmaf(wt, v.x, a0); a1 = fmaf(wt, v.y, a1);
    }
  } else {
    const u16* uin = (const u16*)in;
    for (; j + 8 <= e; j += 8){
      int2 p[8];
      #pragma unroll
      for (int q = 0; q < 8; ++q) p[q] = cpk[j + q];
      u32 u[8]; u16 x2[8];
      #pragma unroll
      for (int q = 0; q < 8; ++q){
        long base = (long)p[q].x * D;
        u[q] = *(const u32*)(uin + base + 2 * lane);
        if (D == 192) x2[q] = uin[base + 128 + lane];
      }
      #pragma unroll
      for (int q = 0; q < 8; ++q){
        float wt = i2f(p[q].y);
        a0 = fmaf(wt, lo2f(u[q]), a0);
        a1 = fmaf(wt, hi2f(u[q]), a1);
        if (D == 192) a2 = fmaf(wt, b2f(x2[q]), a2);
      }
    }
    for (; j < e; ++j){
      int2 p = cpk[j]; float wt = i2f(p.y);
      long base = (long)p.x * D;
      u32 u = *(const u32*)(uin + base + 2 * lane);
      a0 = fmaf(wt, lo2f(u), a0);
      a1 = fmaf(wt, hi2f(u), a1);
      if (D == 192) a2 = fmaf(wt, b2f(uin[base + 128 + lane]), a2);
    }
  }
  u16* q = out + (long)wid * D;
  *(u32*)(q + 2 * lane) = (u32)f2b(a0) | ((u32)f2b(a1) << 16);
  if (D == 192) q[128 + lane] = f2b(a2);
}

// ---------------- generic MFMA GEMM (unchanged) ----------------
template<int K, int DOUT, int CT, int RTW, bool RELU, int AMODE, int OMODE>
__global__ __launch_bounds__(256) void k_mm(const u16* __restrict__ A, const void* __restrict__ A2,
     const void* __restrict__ A3, const void* __restrict__ W, const void* __restrict__ bias,
     void* __restrict__ outv, const int* __restrict__ flags){
  constexpr int STEPS = K / 32;
  constexpr int G = DOUT / (16 * CT);
  constexpr int CHUNKS = 6250 / RTW;      // N = 6250 * 16 exactly
  int wid = blockIdx.x * 4 + (threadIdx.x >> 6);
  if (wid >= G * CHUNKS) return;          // wave-uniform exit
  int g = wid % G; long chunk = wid / G;
  int lane = threadIdx.x & 63, n = lane & 15, q = lane >> 4;
  int colOff = g * CT * 16;
  int fm = flags[0];

  short8 B[CT][STEPS];
  float bv[CT];
  #pragma unroll
  for (int ct = 0; ct < CT; ++ct){
    int col = colOff + ct * 16 + n;
    bv[ct] = ldx(bias, col, fm);
    #pragma unroll
    for (int s = 0; s < STEPS; ++s){
      short8 t;
      if (fm){
        #pragma unroll
        for (int j = 0; j < 8; ++j){
          int k = s * 32 + q * 8 + j;
          t[j] = (short)f2b(((const float*)W)[(long)k * DOUT + col]);
        }
      } else {
        #pragma unroll
        for (int j = 0; j < 8; ++j){
          int k = s * 32 + q * 8 + j;
          t[j] = (short)((const u16*)W)[(long)k * DOUT + col];
        }
      }
      B[ct][s] = t;
    }
  }

  for (int rt = 0; rt < RTW; ++rt){
    long rowbase = (chunk * RTW + rt) * 16;
    long arow = rowbase + n;
    v4f acc[CT] = {};
    #pragma unroll
    for (int s = 0; s < STEPS; ++s){
      short8 a;
      if (AMODE == 0){
        a = *(const short8*)(A + arow * K + s * 32 + q * 8);
      } else if (AMODE == 1){
        long base = arow * 128 + s * 32 + q * 8;
        if (fm){
          const float* xp = (const float*)A2 + base;
          const float* dp = (const float*)A3 + base;
          float4 x0 = *(const float4*)xp, x1 = *(const float4*)(xp + 4);
          float4 d0 = *(const float4*)dp, d1 = *(const float4*)(dp + 4);
          a[0] = (short)f2b(x0.x * d0.x); a[1] = (short)f2b(x0.y * d0.y);
          a[2] = (short)f2b(x0.z * d0.z); a[3] = (short)f2b(x0.w * d0.w);
          a[4] = (short)f2b(x1.x * d1.x); a[5] = (short)f2b(x1.y * d1.y);
          a[6] = (short)f2b(x1.z * d1.z); a[7] = (short)f2b(x1.w * d1.w);
        } else {
          short8 xv = *(const short8*)((const u16*)A2 + base);
          short8 dv = *(const short8*)((const u16*)A3 + base);
          #pragma unroll
          for (int j = 0; j < 8; ++j) a[j] = (short)f2b(b2f((u16)xv[j]) * b2f((u16)dv[j]));
        }
      } else { // AMODE==2: concat(hemb[N,128], y[N,32]), K=160
        if (s < 4) a = *(const short8*)(A + arow * 128 + s * 32 + q * 8);
        else       a = *(const short8*)((const u16*)A2 + arow * 32 + q * 8);
      }
      #pragma unroll
      for (int ct = 0; ct < CT; ++ct)
        acc[ct] = __builtin_amdgcn_mfma_f32_16x16x32_bf16(a, B[ct][s], acc[ct], 0, 0, 0);
    }
    long orow = rowbase + q * 4;
    #pragma unroll
    for (int ct = 0; ct < CT; ++ct){
      int col = colOff + ct * 16 + n;
      #pragma unroll
      for (int r = 0; r < 4; ++r){
        float v = acc[ct][r] + bv[ct];
        if (RELU) v = fmaxf(v, 0.f);
        long oi = (orow + r) * (long)DOUT + col;
        if (OMODE == 1){
          if (fm) ((float*)outv)[oi] = v; else ((u16*)outv)[oi] = f2b(v);
        } else {
          ((u16*)outv)[oi] = f2b(v);
        }
      }
    }
  }
}

// ---------------- gumbel hard one-hot + where(non_label) ----------------
__global__ __launch_bounds__(256) void k_gumbel(const u16* __restrict__ yenc, const void* __restrict__ ug,
                         const void* __restrict__ ylab, const void* __restrict__ nonlab,
                         const int* __restrict__ flags, u16* __restrict__ y){
  int n = blockIdx.x * 256 + threadIdx.x;
  if (n >= NN) return;
  int fm = flags[0], mode = flags[1];
  bool nl;
  if      (mode == 1) nl = ((const int*)nonlab)[n] != 0;
  else if (mode == 3) nl = ((const float*)nonlab)[n] != 0.f;
  else if (mode == 2) nl = ((const u16*)nonlab)[n] != 0;
  else                nl = ((const unsigned char*)nonlab)[n] != 0;
  long base = (long)n * 32;
  if (nl){
    float best = -1e30f; int bi = 0;
    for (int j = 0; j < 32; ++j){
      float uu = ldx(ug, base + j, fm);
      float g = -logf(-logf(uu + 1e-10f) + 1e-10f);
      float v = b2f(yenc[base + j]) + g;
      if (v > best){ best = v; bi = j; }
    }
    for (int j = 0; j < 32; ++j) y[base + j] = (j == bi) ? (u16)0x3F80 : (u16)0;
  } else {
    for (int j = 0; j < 32; ++j)
      y[base + j] = fm ? f2b(((const float*)ylab)[base + j]) : ((const u16*)ylab)[base + j];
  }
}

// ---------------- column-sum of relu'd H [N,128] -> accum[128] ----------------
__global__ __launch_bounds__(256) void k_colsum(const u16* __restrict__ H, float* __restrict__ accum){
  __shared__ float lds[256];
  int t = threadIdx.x, col = t & 127, sub = t >> 7;
  long r0 = (long)blockIdx.x * 400;
  float s = 0.f;
  for (int r = sub; r < 400; r += 2)
    s += b2f(H[(r0 + r) * 128 + col]);
  lds[t] = s; __syncthreads();
  if (t < 128) atomicAdd(&accum[t], lds[t] + lds[t + 128]);
}

// ---------------- tiny tail: r_graph -> hr -> mu/sigma -> z, plus ||z||^2 ----------------
__global__ void k_z(const float* __restrict__ accum,
                    const void* Whr, const void* bhr, const void* Wrh, const void* brh,
                    const void* Wmu, const void* bmu, const void* Wsig, const void* bsig,
                    const void* zeps, float* __restrict__ zout, const int* __restrict__ flags){
  __shared__ float hm[128], rg[128], hr[128], zl[64];
  int t = threadIdx.x, fm = flags[0];
  hm[t] = accum[t] * (1.0f / 100000.0f);
  __syncthreads();
  { float s = ldx(bhr, t, fm);
    for (int k = 0; k < 128; ++k) s = fmaf(hm[k], ldx(Whr, (long)k * 128 + t, fm), s);
    rg[t] = s; }
  __syncthreads();
  { float s = ldx(brh, t, fm);
    for (int k = 0; k < 128; ++k) s = fmaf(rg[k], ldx(Wrh, (long)k * 128 + t, fm), s);
    hr[t] = fmaxf(s, 0.f); }
  __syncthreads();
  if (t < 64){
    float m = ldx(bmu, t, fm), sv = ldx(bsig, t, fm);
    for (int k = 0; k < 128; ++k){
      float h = hr[k];
      m  = fmaf(h, ldx(Wmu,  (long)k * 64 + t, fm), m);
      sv = fmaf(h, ldx(Wsig, (long)k * 64 + t, fm), sv);
    }
    float sig = 0.1f + 0.9f / (1.f + expf(-sv));
    float z = fmaf(sig, ldx(zeps, t, fm), m);
    zl[t] = z; zout[t] = z;
  }
  __syncthreads();
  if (t == 0){ float ss = 0.f; for (int j = 0; j < 64; ++j) ss += zl[j] * zl[j]; zout[64] = ss; }
}

// ---------------- row-normalize: H[N,128] (relu'd) + z -> out[N,192] ----------------
__global__ __launch_bounds__(256) void k_norm(const u16* __restrict__ H, const float* __restrict__ zbuf,
                                              u16* __restrict__ out){
  int wid = blockIdx.x * 4 + (threadIdx.x >> 6);
  int lane = threadIdx.x & 63;
  if (wid >= NN) return;
  u32 hv = *(const u32*)(H + (long)wid * 128 + 2 * lane);
  float h0 = lo2f(hv), h1 = hi2f(hv);
  float ss = h0 * h0 + h1 * h1;
  for (int o = 32; o; o >>= 1) ss += __shfl_xor(ss, o);
  float zz = zbuf[64];
  float zv = zbuf[lane];
  float scale = 1.f / (sqrtf(ss + zz) + 1e-6f);
  u16* q = out + (long)wid * 192;
  *(u32*)(q + 2 * lane) = (u32)f2b(h0 * scale) | ((u32)f2b(h1 * scale) << 16);
  q[128 + lane] = f2b(zv * scale);
}

extern "C" void kernel_launch(void* const* d_in, const int* in_sizes, int n_in,
                              void* d_out, int out_size, void* d_ws, size_t ws_size,
                              hipStream_t stream){
  const void* x    = d_in[0];
  const void* ylab = d_in[1];
  const int*  ei   = (const int*)d_in[2];
  const void* ew   = d_in[3];
  const void* nonlab = d_in[4];
  const void* dm   = d_in[5];
  const void* ug   = d_in[6];
  const void* zeps = d_in[7];
  const void* Wg1 = d_in[8],  *bg1 = d_in[9];
  const void* Wg2 = d_in[10], *bg2 = d_in[11];
  const void* Wxy = d_in[12], *bxy = d_in[13];
  const void* Whr = d_in[14], *bhr = d_in[15];
  const void* Wrh = d_in[16], *brh = d_in[17];
  const void* Wmu = d_in[18], *bmu = d_in[19];
  const void* Wsg = d_in[20], *bsg = d_in[21];
  const void* Wxh = d_in[22], *bxh = d_in[23];
  const void* Wh2 = d_in[24], *bh2 = d_in[25];
  const void* Why = d_in[26], *bhy = d_in[27];

  char* ws = (char*)d_ws;
  size_t off = 0;
  auto alloc = [&](size_t bytes){ void* p = ws + off; off += (bytes + 511) & ~(size_t)511; return p; };
  int*   flags  = (int*)  alloc(256);
  int*   cntcur = (int*)  alloc((size_t)NN * 4);
  int*   rowptr = (int*)  alloc((size_t)(NN + 1) * 4);
  int*   part   = (int*)  alloc(1024 * 4);
  float* accum  = (float*)alloc(1024 * 4);        // [0:128) colsum, [128:192) z, [192] ||z||^2
  int2*  cpk    = (int2*) alloc((size_t)EE * 8);
  u16*   B0     = (u16*)  alloc((size_t)NN * 192 * 2);
  u16*   B1     = (u16*)  alloc((size_t)NN * 192 * 2);
  // yenc / ybuf live in B1's tail while B1's first [N,128] holds h_emb
  u16* yencB = B1 + (size_t)NN * 128;   // [N,32] bf16
  u16* ybuf  = B1 + (size_t)NN * 160;   // [N,32] bf16
  // staging for bucketed scatter reuses B0 (dead until SpMM S1 writes it)
  int2* stage = (int2*)B0;

  hipMemsetAsync(cntcur, 0, (size_t)NN * 4, stream);
  hipMemsetAsync(accum, 0, 1024 * 4, stream);
  k_detect<<<1, 256, 0, stream>>>(x, nonlab, flags);
  // CSR build (shared by all 4 SpMMs)
  k_count  <<<EE / 256, 256, 0, stream>>>(ei, cntcur);
  k_scan1  <<<98, 256, 0, stream>>>(cntcur, part);
  k_scan2  <<<1, 128, 0, stream>>>(part, rowptr, 98);
  k_scan3  <<<98, 256, 0, stream>>>(cntcur, part, rowptr);
  k_binit  <<<1, 256, 0, stream>>>(rowptr, part);                       // bcur = rowptr at bucket bases
  k_binA   <<<(EE + 4095) / 4096, 256, 0, stream>>>(ei, ew, part, stage, flags);
  k_binB   <<<NBK, 512, 0, stream>>>(rowptr, stage, cpk);
  // pipeline
  k_spmm<128, true ><<<25000, 256, 0, stream>>>(x,  B0, rowptr, cpk, flags);                 // S1: x->B0
  k_mm<128,128,4,10,true ,0,0><<<313, 256, 0, stream>>>(B0, nullptr, nullptr, Wg1, bg1, B1, flags);   // h_emb->B1
  k_spmm<128, false><<<25000, 256, 0, stream>>>(B1, B0, rowptr, cpk, flags);                 // S2: B1->B0
  k_mm<128,32 ,2,5 ,false,0,0><<<313, 256, 0, stream>>>(B0, nullptr, nullptr, Wg2, bg2, yencB, flags); // y_encode
  k_gumbel<<<(NN + 255) / 256, 256, 0, stream>>>(yencB, ug, ylab, nonlab, flags, ybuf);      // y
  k_mm<160,128,4,10,true ,2,0><<<313, 256, 0, stream>>>(B1, ybuf, nullptr, Wxy, bxy, B0, flags);      // h_enc->B0
  k_colsum<<<250, 256, 0, stream>>>(B0, accum);                                              // colsum(h_enc)
  k_z<<<1, 128, 0, stream>>>(accum, Whr, bhr, Wrh, brh, Wmu, bmu, Wsg, bsg, zeps, accum + 128, flags);
  k_mm<128,128,4,10,true ,1,0><<<313, 256, 0, stream>>>(nullptr, x, dm, Wxh, bxh, B0, flags);         // H=relu(xd@Wxh)->B0
  k_norm<<<25000, 256, 0, stream>>>(B0, accum + 128, B1);                                    // h [N,192]->B1
  k_spmm<192, false><<<25000, 256, 0, stream>>>(B1, B0, rowptr, cpk, flags);                 // S3: B1->B0
  k_mm<192,192,4,10,true ,0,0><<<469, 256, 0, stream>>>(B0, nullptr, nullptr, Wh2, bh2, B1, flags);   // h2->B1
  k_spmm<192, false><<<25000, 256, 0, stream>>>(B1, B0, rowptr, cpk, flags);                 // S4: B1->B0
  k_mm<192,32 ,2,5 ,false,0,1><<<313, 256, 0, stream>>>(B0, nullptr, nullptr, Why, bhy, d_out, flags); // y_pred
}

// Round 2
// 871.336 us; speedup vs baseline: 1.2166x; 1.1358x over previous
//
#include <hip/hip_runtime.h>
#include <hip/hip_bf16.h>

#define NN 100000
#define EE 1600000

typedef unsigned short u16;
typedef unsigned int   u32;
typedef short short8 __attribute__((ext_vector_type(8)));
typedef float v4f    __attribute__((ext_vector_type(4)));

__device__ __forceinline__ float b2f(u16 h){ u32 u = ((u32)h) << 16; return __builtin_bit_cast(float, u); }
__device__ __forceinline__ float lo2f(u32 u){ return __builtin_bit_cast(float, u << 16); }
__device__ __forceinline__ float hi2f(u32 u){ return __builtin_bit_cast(float, u & 0xffff0000u); }
__device__ __forceinline__ u16   f2b(float f){ __hip_bfloat16 h = __float2bfloat16(f); return __builtin_bit_cast(u16, h); }
__device__ __forceinline__ float ldx(const void* p, long i, int fm){
  return fm ? ((const float*)p)[i] : b2f(((const u16*)p)[i]);
}
__device__ __forceinline__ float i2f(int v){ return __builtin_bit_cast(float, v); }

// ---------------- dtype detection (parallel) ----------------
__global__ void k_detect(const void* __restrict__ x, const void* __restrict__ nonlab,
                         int* __restrict__ flags){
  __shared__ int s_bad, s_ni, s_nf, s_nb;
  int t = threadIdx.x;
  if (t == 0){ s_bad = 0; s_ni = 0; s_nf = 0; s_nb = 0; }
  __syncthreads();
  u32 w = ((const u32*)x)[t];
  u32 lo = w & 0xffffu, ex = (lo >> 7) & 0xffu;
  if (lo != 0u && (ex < 100u || ex > 140u)) atomicAdd(&s_bad, 1);
  if (t < 64){
    u32 v = ((const u32*)nonlab)[t];
    if (v > 1u) atomicAdd(&s_ni, 1);
    if (v != 0u && v != 0x3F800000u) atomicAdd(&s_nf, 1);
  }
  if (t < 128){
    u16 h = ((const u16*)nonlab)[t];
    if (h != 0 && h != 0x3F80) atomicAdd(&s_nb, 1);
  }
  __syncthreads();
  if (t == 0){
    flags[0] = (s_bad > 32) ? 1 : 0;
    flags[1] = (s_ni == 0) ? 1 : ((s_nf == 0) ? 3 : ((s_nb == 0) ? 2 : 0));
  }
}

// ---------------- CSR build ----------------
__global__ void k_count(const int* __restrict__ ei, int* __restrict__ cnt){
  int e = blockIdx.x * 256 + threadIdx.x;
  if (e < EE) atomicAdd(&cnt[ei[e]], 1);
}

#define SCAN_C 1024
__global__ void k_scan1(const int* __restrict__ cnt, int* __restrict__ part){
  __shared__ int red[256];
  int b = blockIdx.x, t = threadIdx.x;
  int base = b * SCAN_C + t * 4;
  int s = 0;
  #pragma unroll
  for (int j = 0; j < 4; ++j){ int i = base + j; if (i < NN) s += cnt[i]; }
  red[t] = s; __syncthreads();
  for (int o = 128; o; o >>= 1){ if (t < o) red[t] += red[t + o]; __syncthreads(); }
  if (t == 0) part[b] = red[0];
}
__global__ void k_scan2(int* __restrict__ part, int* __restrict__ rowptr, int nb){
  __shared__ int l[128];
  int t = threadIdx.x;
  int v = (t < nb) ? part[t] : 0;
  l[t] = v; __syncthreads();
  for (int o = 1; o < 128; o <<= 1){
    int x = (t >= o) ? l[t - o] : 0; __syncthreads();
    l[t] += x; __syncthreads();
  }
  if (t < nb) part[t] = l[t] - v;          // exclusive
  if (t == nb - 1) rowptr[NN] = l[t];      // total == EE
}
__global__ void k_scan3(const int* __restrict__ cnt, const int* __restrict__ part,
                        int* __restrict__ rowptr){
  __shared__ int lds[256];
  int b = blockIdx.x, t = threadIdx.x;
  int base = b * SCAN_C + t * 4;
  int v[4]; int s = 0;
  #pragma unroll
  for (int j = 0; j < 4; ++j){ int i = base + j; v[j] = (i < NN) ? cnt[i] : 0; s += v[j]; }
  lds[t] = s; __syncthreads();
  for (int o = 1; o < 256; o <<= 1){
    int x = (t >= o) ? lds[t - o] : 0; __syncthreads();
    lds[t] += x; __syncthreads();
  }
  int excl = lds[t] - s + part[b];
  #pragma unroll
  for (int j = 0; j < 4; ++j){
    int i = base + j;
    if (i < NN){ rowptr[i] = excl; excl += v[j]; }
  }
}

// ---------------- bucketed scatter ----------------
#define BSH 9
#define NBK 196   // ceil(NN / 512)

__global__ void k_binit(const int* __restrict__ rowptr, int* __restrict__ bcur){
  int t = threadIdx.x;
  if (t < NBK) bcur[t] = rowptr[t << BSH];
}

__global__ __launch_bounds__(256) void k_binA(const int* __restrict__ ei, const void* __restrict__ ew,
                      int* __restrict__ bcur, int2* __restrict__ stage,
                      const int* __restrict__ flags){
  __shared__ int lcnt[NBK];
  __shared__ int lbase[NBK];
  int t = threadIdx.x;
  for (int i = t; i < NBK; i += 256) lcnt[i] = 0;
  __syncthreads();
  int fm = flags[0];
  long e0 = (long)blockIdx.x * 4096;
  int bb[16], ord[16], pk[16], wb[16];
  #pragma unroll
  for (int j = 0; j < 16; ++j){
    long e = e0 + j * 256 + t;
    bool v = e < EE;
    int r = v ? ei[e] : 0;
    int c = v ? ei[EE + e] : 0;
    float w = v ? ldx(ew, e, fm) : 0.f;
    int b = r >> BSH;
    bb[j] = v ? b : -1;
    pk[j] = ((r & 511) << 17) | c;   // rowInBucket (9b) | col (17b)
    wb[j] = __builtin_bit_cast(int, w);
    if (v) ord[j] = atomicAdd(&lcnt[b], 1);
  }
  __syncthreads();
  for (int i = t; i < NBK; i += 256){
    int c = lcnt[i];
    lbase[i] = c ? atomicAdd(&bcur[i], c) : 0;
  }
  __syncthreads();
  #pragma unroll
  for (int j = 0; j < 16; ++j){
    if (bb[j] >= 0){
      int pos = lbase[bb[j]] + ord[j];
      stage[pos] = make_int2(pk[j], wb[j]);
    }
  }
}

__global__ __launch_bounds__(512) void k_binB(const int* __restrict__ rowptr,
                      const int2* __restrict__ stage, int2* __restrict__ cpk){
  __shared__ int cur[512];
  int b = blockIdx.x, t = threadIdx.x;
  int r0 = b << BSH;
  int rows = min(512, NN - r0);
  for (int i = t; i < rows; i += 512) cur[i] = rowptr[r0 + i];
  __syncthreads();
  int s = rowptr[r0];
  int e = rowptr[min(r0 + 512, NN)];
  for (int j = s + t; j < e; j += 512){
    int2 v = stage[j];
    int rib = ((u32)v.x) >> 17;
    int col = v.x & 0x1FFFF;
    int pos = atomicAdd(&cur[rib], 1);
    cpk[pos] = make_int2(col, v.y);
  }
}

// ---------------- SpMM D=128: one wave per row, 8 edges in flight ----------------
// AG: additionally computes agg[row] = sum_e w_e * agt[col_e]  (rank-1 z-block support)
template<int D, bool EXT, bool AG>
__global__ __launch_bounds__(256) void k_spmm(const void* __restrict__ in, u16* __restrict__ out,
                       const int* __restrict__ rowptr, const int2* __restrict__ cpk,
                       const int* __restrict__ flags,
                       const float* __restrict__ agt, float* __restrict__ agg){
  int wid  = blockIdx.x * 4 + (threadIdx.x >> 6);
  int lane = threadIdx.x & 63;
  if (wid >= NN) return;
  int fm = EXT ? flags[0] : 0;
  int s = rowptr[wid], e = rowptr[wid + 1];
  float a0 = 0.f, a1 = 0.f, aga = 0.f;
  int j = s;
  if (EXT && fm){
    const float* fin = (const float*)in;
    for (; j + 8 <= e; j += 8){
      int2 p[8];
      #pragma unroll
      for (int q = 0; q < 8; ++q) p[q] = cpk[j + q];
      float2 v[8];
      #pragma unroll
      for (int q = 0; q < 8; ++q) v[q] = *(const float2*)(fin + (long)p[q].x * D + 2 * lane);
      #pragma unroll
      for (int q = 0; q < 8; ++q){
        float wt = i2f(p[q].y);
        a0 = fmaf(wt, v[q].x, a0);
        a1 = fmaf(wt, v[q].y, a1);
      }
    }
    for (; j < e; ++j){
      int2 p = cpk[j]; float wt = i2f(p.y);
      float2 v = *(const float2*)(fin + (long)p.x * D + 2 * lane);
      a0 = fmaf(wt, v.x, a0); a1 = fmaf(wt, v.y, a1);
    }
  } else {
    const u16* uin = (const u16*)in;
    for (; j + 8 <= e; j += 8){
      int2 p[8];
      #pragma unroll
      for (int q = 0; q < 8; ++q) p[q] = cpk[j + q];
      u32 u[8];
      #pragma unroll
      for (int q = 0; q < 8; ++q){
        long base = (long)p[q].x * D;
        u[q] = *(const u32*)(uin + base + 2 * lane);
      }
      if (AG && lane == 0){
        #pragma unroll
        for (int q = 0; q < 8; ++q) aga = fmaf(i2f(p[q].y), agt[p[q].x], aga);
      }
      #pragma unroll
      for (int q = 0; q < 8; ++q){
        float wt = i2f(p[q].y);
        a0 = fmaf(wt, lo2f(u[q]), a0);
        a1 = fmaf(wt, hi2f(u[q]), a1);
      }
    }
    for (; j < e; ++j){
      int2 p = cpk[j]; float wt = i2f(p.y);
      long base = (long)p.x * D;
      u32 u = *(const u32*)(uin + base + 2 * lane);
      a0 = fmaf(wt, lo2f(u), a0);
      a1 = fmaf(wt, hi2f(u), a1);
      if (AG && lane == 0) aga = fmaf(wt, agt[p.x], aga);
    }
  }
  u16* q = out + (long)wid * D;
  *(u32*)(q + 2 * lane) = (u32)f2b(a0) | ((u32)f2b(a1) << 16);
  if (AG && lane == 0) agg[wid] = aga;
}

// ---------------- SpMM D=32: 16 threads per row, 16 rows per block ----------------
// OM==0: bf16 table in -> bf16 out (no bias). OM==1: f32 table in, +bias, out fm? f32 : bf16.
template<int OM>
__global__ __launch_bounds__(256) void k_spmm32(const void* __restrict__ in, void* __restrict__ out,
                       const int* __restrict__ rowptr, const int2* __restrict__ cpk,
                       const int* __restrict__ flags, const void* __restrict__ bias){
  int row = blockIdx.x * 16 + (threadIdx.x >> 4);
  int d = threadIdx.x & 15;
  if (row >= NN) return;
  int fm = OM ? flags[0] : 0;
  int s = rowptr[row], e = rowptr[row + 1];
  float a0 = 0.f, a1 = 0.f;
  if (OM){ a0 = ldx(bias, 2 * d, fm); a1 = ldx(bias, 2 * d + 1, fm); }
  int j = s;
  if (OM){
    const float* fin = (const float*)in;
    for (; j + 4 <= e; j += 4){
      int2 p[4];
      #pragma unroll
      for (int q = 0; q < 4; ++q) p[q] = cpk[j + q];
      float2 v[4];
      #pragma unroll
      for (int q = 0; q < 4; ++q) v[q] = *(const float2*)(fin + (long)p[q].x * 32 + 2 * d);
      #pragma unroll
      for (int q = 0; q < 4; ++q){
        float wt = i2f(p[q].y);
        a0 = fmaf(wt, v[q].x, a0); a1 = fmaf(wt, v[q].y, a1);
      }
    }
    for (; j < e; ++j){
      int2 p = cpk[j]; float wt = i2f(p.y);
      float2 v = *(const float2*)(fin + (long)p.x * 32 + 2 * d);
      a0 = fmaf(wt, v.x, a0); a1 = fmaf(wt, v.y, a1);
    }
  } else {
    const u16* uin = (const u16*)in;
    for (; j + 4 <= e; j += 4){
      int2 p[4];
      #pragma unroll
      for (int q = 0; q < 4; ++q) p[q] = cpk[j + q];
      u32 u[4];
      #pragma unroll
      for (int q = 0; q < 4; ++q) u[q] = *(const u32*)(uin + (long)p[q].x * 32 + 2 * d);
      #pragma unroll
      for (int q = 0; q < 4; ++q){
        float wt = i2f(p[q].y);
        a0 = fmaf(wt, lo2f(u[q]), a0); a1 = fmaf(wt, hi2f(u[q]), a1);
      }
    }
    for (; j < e; ++j){
      int2 p = cpk[j]; float wt = i2f(p.y);
      u32 u = *(const u32*)(uin + (long)p.x * 32 + 2 * d);
      a0 = fmaf(wt, lo2f(u), a0); a1 = fmaf(wt, hi2f(u), a1);
    }
  }
  if (OM && fm){
    *(float2*)((float*)out + (long)row * 32 + 2 * d) = make_float2(a0, a1);
  } else {
    u32 w = (u32)f2b(a0) | ((u32)f2b(a1) << 16);
    *(u32*)((u16*)out + (long)row * 32 + 2 * d) = w;
  }
}

// ---------------- generic MFMA GEMM ----------------
// AMODE 3: A = [N,128] bf16 (s<4); s>=4: a = agg[row] * zvec[(s-4)*32 + ...]  (rank-1 block)
template<int K, int DOUT, int CT, int RTW, bool RELU, int AMODE, int OMODE>
__global__ __launch_bounds__(256) void k_mm(const u16* __restrict__ A, const void* __restrict__ A2,
     const void* __restrict__ A3, const void* __restrict__ W, const void* __restrict__ bias,
     void* __restrict__ outv, const int* __restrict__ flags){
  constexpr int STEPS = K / 32;
  constexpr int G = DOUT / (16 * CT);
  constexpr int CHUNKS = 6250 / RTW;      // N = 6250 * 16 exactly
  int wid = blockIdx.x * 4 + (threadIdx.x >> 6);
  if (wid >= G * CHUNKS) return;          // wave-uniform exit
  int g = wid % G; long chunk = wid / G;
  int lane = threadIdx.x & 63, n = lane & 15, q = lane >> 4;
  int colOff = g * CT * 16;
  int fm = flags[0];

  short8 B[CT][STEPS];
  float bv[CT];
  #pragma unroll
  for (int ct = 0; ct < CT; ++ct){
    int col = colOff + ct * 16 + n;
    bv[ct] = ldx(bias, col, fm);
    #pragma unroll
    for (int s = 0; s < STEPS; ++s){
      short8 t;
      if (fm){
        #pragma unroll
        for (int j = 0; j < 8; ++j){
          int k = s * 32 + q * 8 + j;
          t[j] = (short)f2b(((const float*)W)[(long)k * DOUT + col]);
        }
      } else {
        #pragma unroll
        for (int j = 0; j < 8; ++j){
          int k = s * 32 + q * 8 + j;
          t[j] = (short)((const u16*)W)[(long)k * DOUT + col];
        }
      }
      B[ct][s] = t;
    }
  }

  for (int rt = 0; rt < RTW; ++rt){
    long rowbase = (chunk * RTW + rt) * 16;
    long arow = rowbase + n;
    float agr = (AMODE == 3) ? ((const float*)A2)[arow] : 0.f;
    v4f acc[CT] = {};
    #pragma unroll
    for (int s = 0; s < STEPS; ++s){
      short8 a;
      if (AMODE == 0){
        a = *(const short8*)(A + arow * K + s * 32 + q * 8);
      } else if (AMODE == 1){
        long base = arow * 128 + s * 32 + q * 8;
        if (fm){
          const float* xp = (const float*)A2 + base;
          const float* dp = (const float*)A3 + base;
          float4 x0 = *(const float4*)xp, x1 = *(const float4*)(xp + 4);
          float4 d0 = *(const float4*)dp, d1 = *(const float4*)(dp + 4);
          a[0] = (short)f2b(x0.x * d0.x); a[1] = (short)f2b(x0.y * d0.y);
          a[2] = (short)f2b(x0.z * d0.z); a[3] = (short)f2b(x0.w * d0.w);
          a[4] = (short)f2b(x1.x * d1.x); a[5] = (short)f2b(x1.y * d1.y);
          a[6] = (short)f2b(x1.z * d1.z); a[7] = (short)f2b(x1.w * d1.w);
        } else {
          short8 xv = *(const short8*)((const u16*)A2 + base);
          short8 dv = *(const short8*)((const u16*)A3 + base);
          #pragma unroll
          for (int j = 0; j < 8; ++j) a[j] = (short)f2b(b2f((u16)xv[j]) * b2f((u16)dv[j]));
        }
      } else if (AMODE == 2){ // concat(hemb[N,128], y[N,32]), K=160
        if (s < 4) a = *(const short8*)(A + arow * 128 + s * 32 + q * 8);
        else       a = *(const short8*)((const u16*)A2 + arow * 32 + q * 8);
      } else { // AMODE==3: concat(spmmH[N,128], agg*z[64]), K=192
        if (s < 4) a = *(const short8*)(A + arow * 128 + s * 32 + q * 8);
        else {
          const float* zv = (const float*)A3;
          #pragma unroll
          for (int j = 0; j < 8; ++j) a[j] = (short)f2b(agr * zv[(s - 4) * 32 + q * 8 + j]);
        }
      }
      #pragma unroll
      for (int ct = 0; ct < CT; ++ct)
        acc[ct] = __builtin_amdgcn_mfma_f32_16x16x32_bf16(a, B[ct][s], acc[ct], 0, 0, 0);
    }
    long orow = rowbase + q * 4;
    #pragma unroll
    for (int ct = 0; ct < CT; ++ct){
      int col = colOff + ct * 16 + n;
      #pragma unroll
      for (int r = 0; r < 4; ++r){
        float v = acc[ct][r] + bv[ct];
        if (RELU) v = fmaxf(v, 0.f);
        long oi = (orow + r) * (long)DOUT + col;
        if (OMODE == 1){
          if (fm) ((float*)outv)[oi] = v; else ((u16*)outv)[oi] = f2b(v);
        } else if (OMODE == 2){
          ((float*)outv)[oi] = v;
        } else {
          ((u16*)outv)[oi] = f2b(v);
        }
      }
    }
  }
}

// ---------------- gumbel hard one-hot + where(non_label); bg2 folded in ----------------
__global__ __launch_bounds__(256) void k_gumbel(const u16* __restrict__ yenc, const void* __restrict__ ug,
                         const void* __restrict__ ylab, const void* __restrict__ nonlab,
                         const int* __restrict__ flags, u16* __restrict__ y,
                         const void* __restrict__ bg2){
  int n = blockIdx.x * 256 + threadIdx.x;
  if (n >= NN) return;
  int fm = flags[0], mode = flags[1];
  bool nl;
  if      (mode == 1) nl = ((const int*)nonlab)[n] != 0;
  else if (mode == 3) nl = ((const float*)nonlab)[n] != 0.f;
  else if (mode == 2) nl = ((const u16*)nonlab)[n] != 0;
  else                nl = ((const unsigned char*)nonlab)[n] != 0;
  long base = (long)n * 32;
  if (nl){
    float best = -1e30f; int bi = 0;
    for (int j = 0; j < 32; ++j){
      float uu = ldx(ug, base + j, fm);
      float g = -logf(-logf(uu + 1e-10f) + 1e-10f);
      float v = b2f(yenc[base + j]) + ldx(bg2, j, fm) + g;
      if (v > best){ best = v; bi = j; }
    }
    for (int j = 0; j < 32; ++j) y[base + j] = (j == bi) ? (u16)0x3F80 : (u16)0;
  } else {
    for (int j = 0; j < 32; ++j)
      y[base + j] = fm ? f2b(((const float*)ylab)[base + j]) : ((const u16*)ylab)[base + j];
  }
}

// ---------------- column-sum of relu'd H [N,128] -> accum[128] ----------------
__global__ __launch_bounds__(256) void k_colsum(const u16* __restrict__ H, float* __restrict__ accum){
  __shared__ float lds[256];
  int t = threadIdx.x, col = t & 127, sub = t >> 7;
  long r0 = (long)blockIdx.x * 400;
  float s = 0.f;
  for (int r = sub; r < 400; r += 2)
    s += b2f(H[(r0 + r) * 128 + col]);
  lds[t] = s; __syncthreads();
  if (t < 128) atomicAdd(&accum[t], lds[t] + lds[t + 128]);
}

// ---------------- tiny tail: r_graph -> hr -> mu/sigma -> z, plus ||z||^2 ----------------
__global__ void k_z(const float* __restrict__ accum,
                    const void* Whr, const void* bhr, const void* Wrh, const void* brh,
                    const void* Wmu, const void* bmu, const void* Wsig, const void* bsig,
                    const void* zeps, float* __restrict__ zout, const int* __restrict__ flags){
  __shared__ float hm[128], rg[128], hr[128], zl[64];
  int t = threadIdx.x, fm = flags[0];
  hm[t] = accum[t] * (1.0f / 100000.0f);
  __syncthreads();
  { float s = ldx(bhr, t, fm);
    for (int k = 0; k < 128; ++k) s = fmaf(hm[k], ldx(Whr, (long)k * 128 + t, fm), s);
    rg[t] = s; }
  __syncthreads();
  { float s = ldx(brh, t, fm);
    for (int k = 0; k < 128; ++k) s = fmaf(rg[k], ldx(Wrh, (long)k * 128 + t, fm), s);
    hr[t] = fmaxf(s, 0.f); }
  __syncthreads();
  if (t < 64){
    float m = ldx(bmu, t, fm), sv = ldx(bsig, t, fm);
    for (int k = 0; k < 128; ++k){
      float h = hr[k];
      m  = fmaf(h, ldx(Wmu,  (long)k * 64 + t, fm), m);
      sv = fmaf(h, ldx(Wsig, (long)k * 64 + t, fm), sv);
    }
    float sig = 0.1f + 0.9f / (1.f + expf(-sv));
    float z = fmaf(sig, ldx(zeps, t, fm), m);
    zl[t] = z; zout[t] = z;
  }
  __syncthreads();
  if (t == 0){ float ss = 0.f; for (int j = 0; j < 64; ++j) ss += zl[j] * zl[j]; zout[64] = ss; }
}

// ---------------- row-normalize: H[N,128] + z -> Hs[N,128] bf16, ag[N] f32 ----------------
__global__ __launch_bounds__(256) void k_norm(const u16* __restrict__ H, const float* __restrict__ zbuf,
                                              u16* __restrict__ outHs, float* __restrict__ ag){
  int wid = blockIdx.x * 4 + (threadIdx.x >> 6);
  int lane = threadIdx.x & 63;
  if (wid >= NN) return;
  u32 hv = *(const u32*)(H + (long)wid * 128 + 2 * lane);
  float h0 = lo2f(hv), h1 = hi2f(hv);
  float ss = h0 * h0 + h1 * h1;
  for (int o = 32; o; o >>= 1) ss += __shfl_xor(ss, o);
  float zz = zbuf[64];
  float scale = 1.f / (sqrtf(ss + zz) + 1e-6f);
  u16* q = outHs + (long)wid * 128;
  *(u32*)(q + 2 * lane) = (u32)f2b(h0 * scale) | ((u32)f2b(h1 * scale) << 16);
  if (lane == 0) ag[wid] = scale;
}

extern "C" void kernel_launch(void* const* d_in, const int* in_sizes, int n_in,
                              void* d_out, int out_size, void* d_ws, size_t ws_size,
                              hipStream_t stream){
  const void* x    = d_in[0];
  const void* ylab = d_in[1];
  const int*  ei   = (const int*)d_in[2];
  const void* ew   = d_in[3];
  const void* nonlab = d_in[4];
  const void* dm   = d_in[5];
  const void* ug   = d_in[6];
  const void* zeps = d_in[7];
  const void* Wg1 = d_in[8],  *bg1 = d_in[9];
  const void* Wg2 = d_in[10], *bg2 = d_in[11];
  const void* Wxy = d_in[12], *bxy = d_in[13];
  const void* Whr = d_in[14], *bhr = d_in[15];
  const void* Wrh = d_in[16], *brh = d_in[17];
  const void* Wmu = d_in[18], *bmu = d_in[19];
  const void* Wsg = d_in[20], *bsg = d_in[21];
  const void* Wxh = d_in[22], *bxh = d_in[23];
  const void* Wh2 = d_in[24], *bh2 = d_in[25];
  const void* Why = d_in[26], *bhy = d_in[27];

  char* ws = (char*)d_ws;
  size_t off = 0;
  auto alloc = [&](size_t bytes){ void* p = ws + off; off += (bytes + 511) & ~(size_t)511; return p; };
  int*   flags  = (int*)  alloc(256);
  int*   cntcur = (int*)  alloc((size_t)NN * 4);
  int*   rowptr = (int*)  alloc((size_t)(NN + 1) * 4);
  int*   part   = (int*)  alloc(1024 * 4);
  float* accum  = (float*)alloc(1024 * 4);   // [0:128) colsum, [128:192) z, [192] ||z||^2, [256:448) zeros
  float* AG1    = (float*)alloc((size_t)NN * 4);   // per-row norm scale
  float* AG2    = (float*)alloc((size_t)NN * 4);   // spmm of scale
  int2*  cpk    = (int2*) alloc((size_t)EE * 8);
  u16*   B0     = (u16*)  alloc((size_t)NN * 192 * 2);
  u16*   B1     = (u16*)  alloc((size_t)NN * 192 * 2);
  // tails of B0/B1 host the small [N,32] tensors
  u16* yencB = B1 + (size_t)NN * 128;   // [N,32] bf16
  u16* ybuf  = B1 + (size_t)NN * 160;   // [N,32] bf16
  u16* yproj = B0 + (size_t)NN * 128;   // [N,32] bf16 (h_emb @ Wg2)
  // staging for bucketed scatter reuses B0 (dead until SpMM S1 writes it)
  int2* stage = (int2*)B0;
  float* tbuf = (float*)B0;             // [N,32] f32 (h2 @ Why), reuses B0 at the tail of pipeline
  float* zeros = accum + 256;           // 192 zero floats (memset), zero bf16 too

  hipMemsetAsync(cntcur, 0, (size_t)NN * 4, stream);
  hipMemsetAsync(accum, 0, 1024 * 4, stream);
  k_detect<<<1, 256, 0, stream>>>(x, nonlab, flags);
  // CSR build (shared by all 4 SpMMs)
  k_count  <<<EE / 256, 256, 0, stream>>>(ei, cntcur);
  k_scan1  <<<98, 256, 0, stream>>>(cntcur, part);
  k_scan2  <<<1, 128, 0, stream>>>(part, rowptr, 98);
  k_scan3  <<<98, 256, 0, stream>>>(cntcur, part, rowptr);
  k_binit  <<<1, 256, 0, stream>>>(rowptr, part);
  k_binA   <<<(EE + 4095) / 4096, 256, 0, stream>>>(ei, ew, part, stage, flags);
  k_binB   <<<NBK, 512, 0, stream>>>(rowptr, stage, cpk);
  // pipeline
  k_spmm<128, true , false><<<25000, 256, 0, stream>>>(x, B0, rowptr, cpk, flags, nullptr, nullptr);   // S1: x->B0
  k_mm<128,128,4,10,true ,0,0><<<313, 256, 0, stream>>>(B0, nullptr, nullptr, Wg1, bg1, B1, flags);    // h_emb->B1
  k_mm<128,32 ,2,5 ,false,0,0><<<313, 256, 0, stream>>>(B1, nullptr, nullptr, Wg2, zeros, yproj, flags); // yproj = h_emb@Wg2
  k_spmm32<0><<<6250, 256, 0, stream>>>(yproj, yencB, rowptr, cpk, flags, nullptr);                    // S2': yenc (no bias)
  k_gumbel<<<(NN + 255) / 256, 256, 0, stream>>>(yencB, ug, ylab, nonlab, flags, ybuf, bg2);           // y (bg2 folded)
  k_mm<160,128,4,10,true ,2,0><<<313, 256, 0, stream>>>(B1, ybuf, nullptr, Wxy, bxy, B0, flags);       // h_enc->B0
  k_colsum<<<250, 256, 0, stream>>>(B0, accum);
  k_z<<<1, 128, 0, stream>>>(accum, Whr, bhr, Wrh, brh, Wmu, bmu, Wsg, bsg, zeps, accum + 128, flags);
  k_mm<128,128,4,10,true ,1,0><<<313, 256, 0, stream>>>(nullptr, x, dm, Wxh, bxh, B0, flags);          // H->B0
  k_norm<<<25000, 256, 0, stream>>>(B0, accum + 128, B1, AG1);                                         // Hs->B1, ag->AG1
  k_spmm<128, false, true ><<<25000, 256, 0, stream>>>(B1, B0, rowptr, cpk, flags, AG1, AG2);          // S3: Hs->B0, agg->AG2
  k_mm<192,192,4,10,true ,3,0><<<469, 256, 0, stream>>>(B0, AG2, accum + 128, Wh2, bh2, B1, flags);    // h2->B1 (rank-1 z block)
  k_mm<192,32 ,2,5 ,false,0,2><<<313, 256, 0, stream>>>(B1, nullptr, nullptr, Why, zeros, tbuf, flags); // t = h2@Why (f32)
  k_spmm32<1><<<6250, 256, 0, stream>>>(tbuf, d_out, rowptr, cpk, flags, bhy);                         // S4': y_pred
}